// Round 6
// baseline (1559.646 us; speedup 1.0000x reference)
//
#include <hip/hip_runtime.h>

// RecurrentSNN: B=256, T=1024, F=64, H=512, O=64
// out = concat(mem_rec [B,T,O], spk_rec [B,T,O]) f32.
//
// Round-6: two-kernel split to escape the register cliff (rounds 1-5: the
// fused kernel needs ~222 live floats -> compiler sinks loads (r1/r2),
// spills to scratch (r4) or AGPRs (r5, VGPR=92 + v_accvgpr_read per use).
//
//  K1 snn_cur1: cur1 = x@W_in^T + b_in  (no recurrence -> plain GEMM).
//     thread=h: win in 64 VGPRs; x via same-address vector loads (HW
//     dedups); coalesced 256B stores. ~110 VGPR @ 4 waves/EU.
//  K2 snn_rec: both recurrences, lean: only wout (64) resident.
//     Layer-2 spike multiply via v_readlane: spikes of slice s ARE wave
//     s's lanes -> fma(readlane(rst1,k), wout[k], acc) = 2 VALU/elem,
//     no ballot, no SALU, no LDS broadcast.
//  cur1 staged through d_ws in T-chunks (128 MB -> L3-resident for K2);
//  f32 state round-trip (bit-exact). Fallback: round-5 kernel if ws tiny.
// All arithmetic bit-identical to rounds 1-5 (absmax must be 0.04394531).

namespace {
constexpr int kB = 256;
constexpr int kT = 1024;
constexpr int kF = 64;
constexpr int kH = 512;
constexpr int kO = 64;
constexpr float kBeta = 0.9f;
constexpr float kThresh = 1.0f;
}  // namespace

#define PIN8(p)                                                            \
  asm volatile("" : "+v"((p)[0]), "+v"((p)[1]), "+v"((p)[2]),              \
                    "+v"((p)[3]), "+v"((p)[4]), "+v"((p)[5]),              \
                    "+v"((p)[6]), "+v"((p)[7]))

// ======================= K1: cur1 = x @ W_in^T + b_in ======================
#define FMA4(v, q)                                                         \
  c0 = fmaf((v).x, win[4 * (q) + 0], c0);                                  \
  c1 = fmaf((v).y, win[4 * (q) + 1], c1);                                  \
  c2 = fmaf((v).z, win[4 * (q) + 2], c2);                                  \
  c3 = fmaf((v).w, win[4 * (q) + 3], c3);

__global__ __launch_bounds__(512, 4)
void snn_cur1(const float* __restrict__ x, const float* __restrict__ W_in,
              const float* __restrict__ b_in, float* __restrict__ cur1,
              int t0, int ntc) {
  const int lane = threadIdx.x & 63;
  const int s = threadIdx.x >> 6;
  const int h = s * 64 + lane;
  const int bpb = ntc >> 7;  // blocks per batch element (ntc/128), >=1
  const int b = blockIdx.x / bpb;
  const int tcbase = (blockIdx.x - b * bpb) * 128;

  float win[kF];
  {
    const float4* wiv = reinterpret_cast<const float4*>(W_in) + h * 16;
#pragma unroll
    for (int q = 0; q < 16; ++q) {
      const float4 v = wiv[q];
      win[4 * q + 0] = v.x; win[4 * q + 1] = v.y;
      win[4 * q + 2] = v.z; win[4 * q + 3] = v.w;
    }
  }
  float bin_h = b_in[h];
  PIN8(win + 0);  PIN8(win + 8);  PIN8(win + 16); PIN8(win + 24);
  PIN8(win + 32); PIN8(win + 40); PIN8(win + 48); PIN8(win + 56);
  asm volatile("" : "+v"(bin_h));

  const float* xbase = x + ((size_t)b * kT + t0 + tcbase) * kF;
  float* cbase = cur1 + ((size_t)b * ntc + tcbase) * (size_t)kH + h;

  for (int i = 0; i < 128; ++i) {
    const float4* xp = reinterpret_cast<const float4*>(xbase + (size_t)i * kF);
    // chunk-alternating loads: 2 chunks in flight, live x <= 8 float4.
    float4 xa0 = xp[0], xa1 = xp[1], xa2 = xp[2], xa3 = xp[3];
    float4 xb0 = xp[4], xb1 = xp[5], xb2 = xp[6], xb3 = xp[7];
    float c0 = bin_h, c1 = 0.0f, c2 = 0.0f, c3 = 0.0f;
    FMA4(xa0, 0) FMA4(xa1, 1) FMA4(xa2, 2) FMA4(xa3, 3)
    xa0 = xp[8]; xa1 = xp[9]; xa2 = xp[10]; xa3 = xp[11];
    FMA4(xb0, 4) FMA4(xb1, 5) FMA4(xb2, 6) FMA4(xb3, 7)
    xb0 = xp[12]; xb1 = xp[13]; xb2 = xp[14]; xb3 = xp[15];
    FMA4(xa0, 8) FMA4(xa1, 9) FMA4(xa2, 10) FMA4(xa3, 11)
    FMA4(xb0, 12) FMA4(xb1, 13) FMA4(xb2, 14) FMA4(xb3, 15)
    cbase[(size_t)i * kH] = (c0 + c1) + (c2 + c3);
  }
}

// ======================= K2: the two recurrences ===========================
// spike of in-slice element k = lane k of OWN wave (slice s's h = 64s+k).
#define SPK(k)                                                             \
  __int_as_float(__builtin_amdgcn_readlane(__float_as_int(rst1), (k)))

#define L2RL(q)                                                            \
  a0 = fmaf(SPK(4 * (q) + 0), wout[4 * (q) + 0], a0);                      \
  a1 = fmaf(SPK(4 * (q) + 1), wout[4 * (q) + 1], a1);                      \
  a2 = fmaf(SPK(4 * (q) + 2), wout[4 * (q) + 2], a2);                      \
  a3 = fmaf(SPK(4 * (q) + 3), wout[4 * (q) + 3], a3);

#define LAYER2(buf)                                                        \
  do {                                                                     \
    float a0 = 0.0f, a1 = 0.0f, a2 = 0.0f, a3 = 0.0f;                      \
    L2RL(0) L2RL(1) L2RL(2) L2RL(3) L2RL(4) L2RL(5) L2RL(6) L2RL(7)        \
    L2RL(8) L2RL(9) L2RL(10) L2RL(11) L2RL(12) L2RL(13) L2RL(14) L2RL(15)  \
    red[(buf)][s][o] = (a0 + a1) + (a2 + a3);                              \
  } while (0)

#define BARRIER() asm volatile("s_waitcnt lgkmcnt(0)\n\ts_barrier" ::: "memory")

// consume previously-issued rr: memo update + store step (tt)
#define CONSUME(tt)                                                        \
  do {                                                                     \
    float co = bout_o;                                                     \
    co += rr0; co += rr1; co += rr2; co += rr3;                            \
    co += rr4; co += rr5; co += rr6; co += rr7;                            \
    memo = kBeta * memo + co - rsto;                                       \
    const float so = (memo > kThresh) ? 1.0f : 0.0f;                       \
    rsto = so;                                                             \
    om[(size_t)(tt) * kO] = memo;                                          \
    os[(size_t)(tt) * kO] = so;                                            \
  } while (0)

#define ISSUE_RR(buf)                                                      \
  do {                                                                     \
    rr0 = red[buf][0][o]; rr1 = red[buf][1][o];                            \
    rr2 = red[buf][2][o]; rr3 = red[buf][3][o];                            \
    rr4 = red[buf][4][o]; rr5 = red[buf][5][o];                            \
    rr6 = red[buf][6][o]; rr7 = red[buf][7][o];                            \
  } while (0)

#define L1STEP(PF)                                                         \
  do {                                                                     \
    mem1 = kBeta * mem1 + (PF)-rst1;                                       \
    const bool p = mem1 > kThresh;                                         \
    rst1 = p ? 1.0f : 0.0f;                                                \
  } while (0)

__global__ __launch_bounds__(512, 2)
void snn_rec(const float* __restrict__ cur1, const float* __restrict__ W_out,
             const float* __restrict__ b_out, float* __restrict__ out,
             float* __restrict__ state, int t0, int ntc) {
  const int b = blockIdx.x;
  const int j = threadIdx.x;
  const int o = j & 63;
  const int s = j >> 6;

  __shared__ float red[2][8][64];

  float wout[kO];
  {
    const float4* wov =
        reinterpret_cast<const float4*>(W_out) + o * (kH / 4) + s * 16;
#pragma unroll
    for (int q = 0; q < 16; ++q) {
      const float4 v = wov[q];
      wout[4 * q + 0] = v.x; wout[4 * q + 1] = v.y;
      wout[4 * q + 2] = v.z; wout[4 * q + 3] = v.w;
    }
  }
  float bout_o = b_out[o];
  PIN8(wout + 0);  PIN8(wout + 8);  PIN8(wout + 16); PIN8(wout + 24);
  PIN8(wout + 32); PIN8(wout + 40); PIN8(wout + 48); PIN8(wout + 56);
  asm volatile("" : "+v"(bout_o));

  // ---- state (chunk round-trip, f32 exact) ----
  float* m1s = state;                    // [kB*kH]
  float* r1s = state + kB * kH;          // [kB*kH]
  float* mos = state + 2 * kB * kH;      // [kB*kO]
  float* ros = mos + kB * kO;            // [kB*kO]
  const int idx1 = b * kH + j;
  const int idxo = b * kO + o;

  float mem1 = 0.0f, rst1 = 0.0f, memo = 0.0f, rsto = 0.0f;
  if (t0 != 0) {
    mem1 = m1s[idx1];
    rst1 = r1s[idx1];
    if (s == 0) { memo = mos[idxo]; rsto = ros[idxo]; }
  }

  const float* cp = cur1 + (size_t)b * ntc * kH + j;
  float* om = out + ((size_t)b * kT + t0) * kO + o;
  float* os = om + (size_t)kB * kT * kO;

  float rr0, rr1, rr2, rr3, rr4, rr5, rr6, rr7;
  float pfa = cp[0];
  float pfb = cp[(size_t)1 * kH];

  for (int tc = 0; tc < ntc; tc += 2) {
    // ---- even step tc (buf 0) ----
    L1STEP(pfa);
    {
      const int tp = (tc + 2 < ntc) ? tc + 2 : ntc - 1;
      pfa = cp[(size_t)tp * kH];  // vmcnt-domain, survives the barrier
    }
    LAYER2(0);
    if (s == 0 && tc != 0) CONSUME(tc - 1);  // before barrier: race-free
    BARRIER();
    if (s == 0) ISSUE_RR(0);  // consumed next half-step (latency hidden)

    // ---- odd step tc+1 (buf 1) ----
    L1STEP(pfb);
    {
      const int tp = (tc + 3 < ntc) ? tc + 3 : ntc - 1;
      pfb = cp[(size_t)tp * kH];
    }
    LAYER2(1);
    if (s == 0) CONSUME(tc);
    BARRIER();
    if (s == 0) ISSUE_RR(1);
  }
  // epilogue: last issued rr = step ntc-1
  if (s == 0) CONSUME(ntc - 1);

  // ---- save state ----
  m1s[idx1] = mem1;
  r1s[idx1] = rst1;
  if (s == 0) { mos[idxo] = memo; ros[idxo] = rsto; }
}

// ======================= fallback (round-5, proven) ========================
#define BITF(k) ((((k) < 32 ? (mlo >> (k)) : (mhi >> ((k)-32))) & 1u) \
                 ? 1.0f : 0.0f)

__global__ __launch_bounds__(256)
void warm_x_kernel(const float4* __restrict__ p, int n4) {
  float acc = 0.0f;
  for (int i = blockIdx.x * blockDim.x + threadIdx.x; i < n4;
       i += gridDim.x * blockDim.x) {
    const float4 v = p[i];
    acc += v.x + v.y + v.z + v.w;
  }
  asm volatile("" ::"v"(acc));
}

__global__ __launch_bounds__(512)
__attribute__((amdgpu_waves_per_eu(2, 2)))
void snn_fused5(const float* __restrict__ x, const float* __restrict__ W_in,
                const float* __restrict__ b_in,
                const float* __restrict__ W_out,
                const float* __restrict__ b_out, float* __restrict__ out) {
  const int b = blockIdx.x;
  const int j = threadIdx.x;
  const int o = j & 63;
  const int s = j >> 6;
  __shared__ float red[2][8][64];
  float win[kF];
  {
    const float4* wiv = reinterpret_cast<const float4*>(W_in) + j * 16;
#pragma unroll
    for (int q = 0; q < 16; ++q) {
      const float4 v = wiv[q];
      win[4 * q] = v.x; win[4 * q + 1] = v.y;
      win[4 * q + 2] = v.z; win[4 * q + 3] = v.w;
    }
  }
  float wout[64];
  {
    const float4* wov =
        reinterpret_cast<const float4*>(W_out) + o * 128 + s * 16;
#pragma unroll
    for (int q = 0; q < 16; ++q) {
      const float4 v = wov[q];
      wout[4 * q] = v.x; wout[4 * q + 1] = v.y;
      wout[4 * q + 2] = v.z; wout[4 * q + 3] = v.w;
    }
  }
  float bin_j = b_in[j];
  float bout_o = b_out[o];
  PIN8(win + 0);  PIN8(win + 8);  PIN8(win + 16); PIN8(win + 24);
  PIN8(win + 32); PIN8(win + 40); PIN8(win + 48); PIN8(win + 56);
  PIN8(wout + 0);  PIN8(wout + 8);  PIN8(wout + 16); PIN8(wout + 24);
  PIN8(wout + 32); PIN8(wout + 40); PIN8(wout + 48); PIN8(wout + 56);
  asm volatile("" : "+v"(bin_j), "+v"(bout_o));
  float mem1 = 0.0f, rst1 = 0.0f, memo = 0.0f, rsto = 0.0f;
  unsigned long long mask = 0ull;
  const float4* xv = reinterpret_cast<const float4*>(x + (size_t)b * kT * kF);
  float* out_mem = out + (size_t)b * kT * kO + o;
  float* out_spk = out_mem + (size_t)kB * kT * kO;
  float4 x0, x1, x2, x3, x4, x5, x6, x7, x8, x9, x10, x11, x12, x13, x14, x15;
#define LOADX(tt)                                                          \
  do {                                                                     \
    const float4* xp = xv + (size_t)(tt) * 16;                             \
    x0 = xp[0]; x1 = xp[1]; x2 = xp[2]; x3 = xp[3];                        \
    x4 = xp[4]; x5 = xp[5]; x6 = xp[6]; x7 = xp[7];                        \
    x8 = xp[8]; x9 = xp[9]; x10 = xp[10]; x11 = xp[11];                    \
    x12 = xp[12]; x13 = xp[13]; x14 = xp[14]; x15 = xp[15];                \
  } while (0)
#define L1Q(q)                                                             \
  c0 = fmaf(x##q.x, win[4 * q + 0], c0);                                   \
  c1 = fmaf(x##q.y, win[4 * q + 1], c1);                                   \
  c2 = fmaf(x##q.z, win[4 * q + 2], c2);                                   \
  c3 = fmaf(x##q.w, win[4 * q + 3], c3);
#define LAYER1F()                                                          \
  do {                                                                     \
    float c0 = bin_j, c1 = 0.0f, c2 = 0.0f, c3 = 0.0f;                     \
    L1Q(0) L1Q(1) L1Q(2) L1Q(3) L1Q(4) L1Q(5) L1Q(6) L1Q(7)                \
    L1Q(8) L1Q(9) L1Q(10) L1Q(11) L1Q(12) L1Q(13) L1Q(14) L1Q(15)          \
    const float cur1 = (c0 + c1) + (c2 + c3);                              \
    mem1 = kBeta * mem1 + cur1 - rst1;                                     \
    const bool p = mem1 > kThresh;                                         \
    mask = __ballot(p);                                                    \
    rst1 = p ? 1.0f : 0.0f;                                                \
  } while (0)
#define L2QS(q)                                                            \
  {                                                                        \
    const float f0 = ((mlo >> (4 * (q) + 0)) & 1u) ? 1.0f : 0.0f;          \
    const float f1 = ((mlo >> (4 * (q) + 1)) & 1u) ? 1.0f : 0.0f;          \
    const float f2 = ((mlo >> (4 * (q) + 2)) & 1u) ? 1.0f : 0.0f;          \
    const float f3 = ((mlo >> (4 * (q) + 3)) & 1u) ? 1.0f : 0.0f;          \
    a0 = fmaf(f0, wout[4 * (q) + 0], a0);                                  \
    a1 = fmaf(f1, wout[4 * (q) + 1], a1);                                  \
    a2 = fmaf(f2, wout[4 * (q) + 2], a2);                                  \
    a3 = fmaf(f3, wout[4 * (q) + 3], a3);                                  \
  }
#define L2E(acc, q, i)                                                     \
  acc = acc + __uint_as_float(                                             \
      (unsigned)__builtin_amdgcn_sbfe((int)vmhi, 4 * (q) + (i)-32, 1) &    \
      __float_as_uint(wout[4 * (q) + (i)]));
#define L2QV(q)                                                            \
  { L2E(a0, q, 0) L2E(a1, q, 1) L2E(a2, q, 2) L2E(a3, q, 3) }
#define LAYER2F(buf)                                                       \
  do {                                                                     \
    const unsigned mlo = (unsigned)mask;                                   \
    unsigned vmhi = (unsigned)(mask >> 32);                                \
    asm volatile("" : "+v"(vmhi));                                         \
    float a0 = 0.0f, a1 = 0.0f, a2 = 0.0f, a3 = 0.0f;                      \
    L2QS(0) L2QS(1) L2QS(2) L2QS(3) L2QS(4) L2QS(5) L2QS(6) L2QS(7)        \
    L2QV(8) L2QV(9) L2QV(10) L2QV(11) L2QV(12) L2QV(13) L2QV(14) L2QV(15)  \
    red[(buf)][s][o] = (a0 + a1) + (a2 + a3);                              \
  } while (0)
  LOADX(0);
  LAYER1F();
  LOADX(1);
  for (int t = 1; t < kT; ++t) {
    LAYER2F((t - 1) & 1);
    BARRIER();
    float r0, r1, r2, r3, r4, r5, r6, r7;
    const int buf = (t - 1) & 1;
    if (s == 0) {
      r0 = red[buf][0][o]; r1 = red[buf][1][o];
      r2 = red[buf][2][o]; r3 = red[buf][3][o];
      r4 = red[buf][4][o]; r5 = red[buf][5][o];
      r6 = red[buf][6][o]; r7 = red[buf][7][o];
    }
    LAYER1F();
    const int tn = (t + 1 < kT) ? (t + 1) : (kT - 1);
    LOADX(tn);
    if (s == 0) {
      float co = bout_o;
      co += r0; co += r1; co += r2; co += r3;
      co += r4; co += r5; co += r6; co += r7;
      memo = kBeta * memo + co - rsto;
      const float so = (memo > kThresh) ? 1.0f : 0.0f;
      rsto = so;
      out_mem[(t - 1) * kO] = memo;
      out_spk[(t - 1) * kO] = so;
    }
  }
  LAYER2F((kT - 1) & 1);
  BARRIER();
  if (s == 0) {
    const int buf = (kT - 1) & 1;
    float co = bout_o;
    co += red[buf][0][o]; co += red[buf][1][o];
    co += red[buf][2][o]; co += red[buf][3][o];
    co += red[buf][4][o]; co += red[buf][5][o];
    co += red[buf][6][o]; co += red[buf][7][o];
    memo = kBeta * memo + co - rsto;
    const float so = (memo > kThresh) ? 1.0f : 0.0f;
    out_mem[(kT - 1) * kO] = memo;
    out_spk[(kT - 1) * kO] = so;
  }
}

// ======================= host ==============================================
extern "C" void kernel_launch(void* const* d_in, const int* in_sizes, int n_in,
                              void* d_out, int out_size, void* d_ws,
                              size_t ws_size, hipStream_t stream) {
  const float* x = (const float*)d_in[0];
  const float* W_in = (const float*)d_in[1];
  const float* b_in = (const float*)d_in[2];
  const float* W_out = (const float*)d_in[3];
  const float* b_out = (const float*)d_in[4];
  float* out = (float*)d_out;

  const size_t state_bytes = ((size_t)2 * kB * kH + 2 * kB * kO) * 4;
  int nch = 0;
  for (int c : {4, 8}) {
    const size_t need = (size_t)kB * (kT / c) * kH * 4 + state_bytes;
    if (need <= ws_size) { nch = c; break; }
  }

  if (nch) {
    const int ntc = kT / nch;
    float* cur1 = (float*)d_ws;
    float* state = cur1 + (size_t)kB * ntc * kH;
    const int g1 = kB * (ntc / 128);
    for (int c = 0; c < nch; ++c) {
      hipLaunchKernelGGL(snn_cur1, dim3(g1), dim3(512), 0, stream,
                         x, W_in, b_in, cur1, c * ntc, ntc);
      hipLaunchKernelGGL(snn_rec, dim3(kB), dim3(512), 0, stream,
                         cur1, W_out, b_out, out, state, c * ntc, ntc);
    }
  } else {
    const int n4 = kB * kT * kF / 4;
    hipLaunchKernelGGL(warm_x_kernel, dim3(1024), dim3(256), 0, stream,
                       (const float4*)x, n4);
    hipLaunchKernelGGL(snn_fused5, dim3(kB), dim3(512), 0, stream,
                       x, W_in, b_in, W_out, b_out, out);
  }
}